// Round 1
// baseline (114.319 us; speedup 1.0000x reference)
//
#include <hip/hip_runtime.h>
#include <math.h>

// Chamfer distance, N=M=16384, D=3, fp32.
// sum_i min_j ||p1_i - p2_j|| + sum_j min_i ||p2_j - p1_i||
//
// Strategy: brute-force over all pairs with the ||a||^2+||b||^2-2ab expansion,
// -2*b and ||b||^2 pre-folded into an LDS float4 tile -> 5 VALU ops/pair
// (add + 3 fma + min). Min over squared distances, sqrt deferred.
// Grid split over j-chunks for occupancy; partial mins land in d_ws.

constexpr int NPTS    = 16384;
constexpr int THREADS = 256;
constexpr int NPER    = 2;                       // points1 per thread
constexpr int IBLK    = NPTS / (THREADS * NPER); // 32 i-blocks per pass
constexpr int TS_MAX  = 2048;                    // LDS tile (points), 32 KB
constexpr float INF_F = 3.402823466e+38f;

__global__ __launch_bounds__(THREADS) void chamfer_main(
    const float* __restrict__ p1, const float* __restrict__ p2,
    float* __restrict__ partial, int jsplit) {
  __shared__ float4 lds[TS_MAX];

  const int per_pass = IBLK * jsplit;
  const int b    = blockIdx.x;
  const int pass = b / per_pass;
  const int rem  = b - pass * per_pass;
  const int c    = rem / IBLK;   // j-chunk index
  const int ib   = rem - c * IBLK;

  const float* __restrict__ src = (pass == 0) ? p1 : p2;  // "i" side
  const float* __restrict__ oth = (pass == 0) ? p2 : p1;  // "j" side

  const int tid = threadIdx.x;
  const int i0 = ib * (THREADS * NPER) + tid;
  const int i1 = i0 + THREADS;

  const float ax0 = src[i0 * 3 + 0], ay0 = src[i0 * 3 + 1], az0 = src[i0 * 3 + 2];
  const float ax1 = src[i1 * 3 + 0], ay1 = src[i1 * 3 + 1], az1 = src[i1 * 3 + 2];
  const float sa0 = fmaf(ax0, ax0, fmaf(ay0, ay0, az0 * az0));
  const float sa1 = fmaf(ax1, ax1, fmaf(ay1, ay1, az1 * az1));

  const int jchunk = NPTS / jsplit;
  const int j0 = c * jchunk;

  float m0a = INF_F, m0b = INF_F, m1a = INF_F, m1b = INF_F;

  for (int t0 = 0; t0 < jchunk; t0 += TS_MAX) {
    const int ts = (jchunk - t0 < TS_MAX) ? (jchunk - t0) : TS_MAX;
    __syncthreads();  // protect LDS from previous tile's readers
    for (int p = tid; p < ts; p += THREADS) {
      const int gj = (j0 + t0 + p) * 3;
      const float x = oth[gj + 0], y = oth[gj + 1], z = oth[gj + 2];
      lds[p] = make_float4(-2.0f * x, -2.0f * y, -2.0f * z,
                           fmaf(x, x, fmaf(y, y, z * z)));
    }
    __syncthreads();

#pragma unroll 4
    for (int p = 0; p < ts; p += 2) {
      const float4 q = lds[p];
      const float4 r = lds[p + 1];
      const float tq0 = sa0 + q.w;
      const float tq1 = sa1 + q.w;
      const float tr0 = sa0 + r.w;
      const float tr1 = sa1 + r.w;
      const float dq0 = fmaf(ax0, q.x, fmaf(ay0, q.y, fmaf(az0, q.z, tq0)));
      const float dq1 = fmaf(ax1, q.x, fmaf(ay1, q.y, fmaf(az1, q.z, tq1)));
      const float dr0 = fmaf(ax0, r.x, fmaf(ay0, r.y, fmaf(az0, r.z, tr0)));
      const float dr1 = fmaf(ax1, r.x, fmaf(ay1, r.y, fmaf(az1, r.z, tr1)));
      m0a = fminf(m0a, dq0);
      m1a = fminf(m1a, dq1);
      m0b = fminf(m0b, dr0);
      m1b = fminf(m1b, dr1);
    }
  }

  const float m0 = fminf(m0a, m0b);
  const float m1 = fminf(m1a, m1b);
  partial[(pass * jsplit + c) * NPTS + i0] = m0;
  partial[(pass * jsplit + c) * NPTS + i1] = m1;
}

// One thread per point (2*16384 total): min over jsplit partials, sqrt,
// block-sum -> bsum[blockIdx].
__global__ __launch_bounds__(THREADS) void chamfer_combine(
    const float* __restrict__ partial, float* __restrict__ bsum, int jsplit) {
  const int p = blockIdx.x * THREADS + threadIdx.x;  // 0..32767
  const int pass = p >> 14;
  const int i = p & (NPTS - 1);
  const float* __restrict__ base = partial + pass * jsplit * NPTS + i;

  float m = INF_F;
  for (int c = 0; c < jsplit; ++c) m = fminf(m, base[c * NPTS]);
  float d = sqrtf(fmaxf(m, 0.0f));

  for (int off = 32; off > 0; off >>= 1) d += __shfl_down(d, off, 64);
  __shared__ float red[THREADS / 64];
  const int wave = threadIdx.x >> 6;
  const int lane = threadIdx.x & 63;
  if (lane == 0) red[wave] = d;
  __syncthreads();
  if (threadIdx.x == 0) {
    float s = 0.0f;
    for (int w = 0; w < THREADS / 64; ++w) s += red[w];
    bsum[blockIdx.x] = s;
  }
}

__global__ __launch_bounds__(128) void chamfer_final(
    const float* __restrict__ bsum, float* __restrict__ out) {
  const int tid = threadIdx.x;  // 128 threads, reads 128 block sums
  float s = bsum[tid];
  for (int off = 32; off > 0; off >>= 1) s += __shfl_down(s, off, 64);
  __shared__ float red[2];
  if ((tid & 63) == 0) red[tid >> 6] = s;
  __syncthreads();
  if (tid == 0) out[0] = red[0] + red[1];
}

extern "C" void kernel_launch(void* const* d_in, const int* in_sizes, int n_in,
                              void* d_out, int out_size, void* d_ws, size_t ws_size,
                              hipStream_t stream) {
  const float* p1 = (const float*)d_in[0];
  const float* p2 = (const float*)d_in[1];
  float* out = (float*)d_out;
  float* ws = (float*)d_ws;

  // jsplit: j-range chunks per pass (occupancy). Needs (2*jsplit*NPTS+128)
  // floats of scratch; degrade if ws is small.
  int jsplit = 16;
  while (jsplit > 1 &&
         (size_t)(2 * jsplit * NPTS + 128) * sizeof(float) > ws_size) {
    jsplit >>= 1;
  }

  float* partial = ws;
  float* bsum = ws + (size_t)2 * jsplit * NPTS;

  const int main_grid = 2 * IBLK * jsplit;             // 1024 @ jsplit=16
  const int comb_grid = (2 * NPTS) / THREADS;          // 128

  chamfer_main<<<main_grid, THREADS, 0, stream>>>(p1, p2, partial, jsplit);
  chamfer_combine<<<comb_grid, THREADS, 0, stream>>>(partial, bsum, jsplit);
  chamfer_final<<<1, 128, 0, stream>>>(bsum, out);
}

// Round 2
// 104.669 us; speedup vs baseline: 1.0922x; 1.0922x over previous
//
#include <hip/hip_runtime.h>
#include <math.h>

// Chamfer distance, N=M=16384, D=3, fp32.
// sum_i min_j ||p1_i - p2_j|| + sum_j min_i ||p2_j - p1_i||
//
// R2: (a) hoist ||a||^2 out of the j-loop (min commutes with +const):
//     inner = min_j(||b||^2 - 2 a.b), 4 -> 3 fma + 1 min per pair;
//     (b) pack pairs of i-points as float2 and use __builtin_elementwise_fma
//     -> v_pk_fma_f32 (VOP3P) => 2.5 VALU instr/pair;
//     (c) fuse combine+final into one kernel via memsetAsync + atomicAdd.

typedef float v2f __attribute__((ext_vector_type(2)));

constexpr int NPTS    = 16384;
constexpr int THREADS = 256;
constexpr int NPER    = 4;                       // points1 per thread
constexpr int IBLK    = NPTS / (THREADS * NPER); // 16 i-blocks per pass
constexpr int TS      = 512;                     // LDS tile (points), 8 KB
constexpr float INF_F = 3.402823466e+38f;

static __device__ __forceinline__ v2f vfma(v2f a, v2f b, v2f c) {
  return __builtin_elementwise_fma(a, b, c);
}

__global__ __launch_bounds__(THREADS) void chamfer_main(
    const float* __restrict__ p1, const float* __restrict__ p2,
    float* __restrict__ partial, int jsplit) {
  __shared__ float4 lds[TS];

  const int per_pass = IBLK * jsplit;
  const int b    = blockIdx.x;
  const int pass = b / per_pass;
  const int rem  = b - pass * per_pass;
  const int c    = rem / IBLK;   // j-chunk index
  const int ib   = rem - c * IBLK;

  const float* __restrict__ src = (pass == 0) ? p1 : p2;  // "i" side
  const float* __restrict__ oth = (pass == 0) ? p2 : p1;  // "j" side

  const int tid = threadIdx.x;
  const int i0 = ib * (THREADS * NPER) + tid;
  const int i1 = i0 + THREADS;
  const int i2 = i0 + 2 * THREADS;
  const int i3 = i0 + 3 * THREADS;

  const v2f ax01 = {src[i0 * 3 + 0], src[i1 * 3 + 0]};
  const v2f ay01 = {src[i0 * 3 + 1], src[i1 * 3 + 1]};
  const v2f az01 = {src[i0 * 3 + 2], src[i1 * 3 + 2]};
  const v2f ax23 = {src[i2 * 3 + 0], src[i3 * 3 + 0]};
  const v2f ay23 = {src[i2 * 3 + 1], src[i3 * 3 + 1]};
  const v2f az23 = {src[i2 * 3 + 2], src[i3 * 3 + 2]};

  const int jchunk = NPTS / jsplit;
  const int j0 = c * jchunk;

  // running min of (||b||^2 - 2 a.b); ||a||^2 re-added in the reduce kernel
  v2f m01 = {INF_F, INF_F};
  v2f m23 = {INF_F, INF_F};

  for (int t0 = 0; t0 < jchunk; t0 += TS) {
    const int ts = (jchunk - t0 < TS) ? (jchunk - t0) : TS;
    __syncthreads();  // protect LDS from previous tile's readers
    for (int p = tid; p < ts; p += THREADS) {
      const int gj = (j0 + t0 + p) * 3;
      const float x = oth[gj + 0], y = oth[gj + 1], z = oth[gj + 2];
      lds[p] = make_float4(-2.0f * x, -2.0f * y, -2.0f * z,
                           fmaf(x, x, fmaf(y, y, z * z)));
    }
    __syncthreads();

#pragma unroll 8
    for (int p = 0; p < ts; ++p) {
      const float4 q = lds[p];
      const v2f bx = {q.x, q.x};
      const v2f by = {q.y, q.y};
      const v2f bz = {q.z, q.z};
      const v2f bw = {q.w, q.w};
      const v2f d01 = vfma(ax01, bx, vfma(ay01, by, vfma(az01, bz, bw)));
      const v2f d23 = vfma(ax23, bx, vfma(ay23, by, vfma(az23, bz, bw)));
      m01 = __builtin_elementwise_min(m01, d01);
      m23 = __builtin_elementwise_min(m23, d23);
    }
  }

  float* dst = partial + (size_t)(pass * jsplit + c) * NPTS;
  dst[i0] = m01.x;
  dst[i1] = m01.y;
  dst[i2] = m23.x;
  dst[i3] = m23.y;
}

// One thread per point (2*16384): min over jsplit partials, re-add ||a||^2,
// sqrt, block-sum, one atomicAdd per block into out[0] (zeroed by memsetAsync).
__global__ __launch_bounds__(THREADS) void chamfer_reduce(
    const float* __restrict__ p1, const float* __restrict__ p2,
    const float* __restrict__ partial, float* __restrict__ out, int jsplit) {
  const int p = blockIdx.x * THREADS + threadIdx.x;  // 0..32767
  const int pass = p >> 14;
  const int i = p & (NPTS - 1);
  const float* __restrict__ pts = (pass == 0) ? p1 : p2;

  const float x = pts[i * 3 + 0], y = pts[i * 3 + 1], z = pts[i * 3 + 2];
  const float sa = fmaf(x, x, fmaf(y, y, z * z));

  const float* __restrict__ base = partial + (size_t)pass * jsplit * NPTS + i;
  float m = INF_F;
  for (int c = 0; c < jsplit; ++c) m = fminf(m, base[(size_t)c * NPTS]);
  float d = sqrtf(fmaxf(sa + m, 0.0f));

  for (int off = 32; off > 0; off >>= 1) d += __shfl_down(d, off, 64);
  __shared__ float red[THREADS / 64];
  const int wave = threadIdx.x >> 6;
  const int lane = threadIdx.x & 63;
  if (lane == 0) red[wave] = d;
  __syncthreads();
  if (threadIdx.x == 0) {
    float s = 0.0f;
    for (int w = 0; w < THREADS / 64; ++w) s += red[w];
    atomicAdd(out, s);
  }
}

extern "C" void kernel_launch(void* const* d_in, const int* in_sizes, int n_in,
                              void* d_out, int out_size, void* d_ws, size_t ws_size,
                              hipStream_t stream) {
  const float* p1 = (const float*)d_in[0];
  const float* p2 = (const float*)d_in[1];
  float* out = (float*)d_out;
  float* partial = (float*)d_ws;

  // jsplit: j-range chunks per pass. Scratch need: 2*jsplit*NPTS floats.
  int jsplit = 32;
  while (jsplit > 1 &&
         (size_t)(2 * jsplit * NPTS) * sizeof(float) > ws_size) {
    jsplit >>= 1;
  }

  const int main_grid = 2 * IBLK * jsplit;     // 1024 @ jsplit=32
  const int red_grid  = (2 * NPTS) / THREADS;  // 128

  hipMemsetAsync(out, 0, sizeof(float), stream);
  chamfer_main<<<main_grid, THREADS, 0, stream>>>(p1, p2, partial, jsplit);
  chamfer_reduce<<<red_grid, THREADS, 0, stream>>>(p1, p2, partial, out, jsplit);
}